// Round 4
// baseline (17988.702 us; speedup 1.0000x reference)
//
#include <hip/hip_runtime.h>
#include <hip/hip_bf16.h>

#define L_SIZE 80000
#define C_SIZE 120000
#define N_EDGES 480000
#define DIM 128
#define GDIM 512
#define N_ITER 8

typedef __attribute__((ext_vector_type(8))) short short8;   // 8 bf16 (4 VGPR) MFMA frag
typedef __attribute__((ext_vector_type(4))) float f32x4;    // MFMA acc frag

__device__ __forceinline__ ushort f2bf(float f) {           // fp32 -> bf16 RNE
    uint u = __float_as_uint(f);
    u = u + 0x7FFFu + ((u >> 16) & 1u);
    return (ushort)(u >> 16);
}
__device__ __forceinline__ float bf2f(ushort h) {
    return __uint_as_float(((uint)h) << 16);
}
__device__ __forceinline__ float sigmf(float x) { return 1.f / (1.f + __expf(-x)); }
__device__ __forceinline__ float tanh_f(float x) {
    float e = __expf(2.f * x);
    return 1.f - 2.f / (e + 1.f);
}
__device__ __forceinline__ f32x4 fzero4() {
    f32x4 v; v[0] = v[1] = v[2] = v[3] = 0.f; return v;
}

// ---------------------------------------------------------------------------
// Stage fp32 [nrows,128] rows (rowBase..)^rowXor into LDS as TWO bf16 planes:
// hi at dst, lo at dst + nrows*128 (split-bf16: v = hi + lo + O(2^-17 v)).
// Row stride 256B, XOR-swizzled: byte ^= (row&7)<<4 (conflict-free b128 reads).
// ---------------------------------------------------------------------------
__device__ __forceinline__ void stageA2(const float* __restrict__ src, int rowBase,
                                        int rowXor, ushort* dst, int tid, int nrows)
{
    const int planeB = nrows * 256;   // bytes per plane
    for (int idx = tid * 8; idx < nrows * 128; idx += 512 * 8) {
        int r = idx >> 7, k8 = idx & 127;
        const float* p = src + (size_t)((rowBase + r) ^ rowXor) * DIM + k8;
        float4 v0 = *(const float4*)p;
        float4 v1 = *(const float4*)(p + 4);
        float f[8] = {v0.x, v0.y, v0.z, v0.w, v1.x, v1.y, v1.z, v1.w};
        short8 hi, lo;
        #pragma unroll
        for (int j = 0; j < 8; ++j) {
            ushort h = f2bf(f[j]);
            hi[j] = (short)h;
            lo[j] = (short)f2bf(f[j] - bf2f(h));
        }
        int boff = r * 256 + ((k8 * 2) ^ ((r & 7) << 4));
        *(short8*)((char*)dst + boff) = hi;
        *(short8*)((char*)dst + planeB + boff) = lo;
    }
}

// A-frag: a[j] = A[mi*16 + (lane&15)][k0 + (lane>>4)*8 + j]  (swizzled LDS plane)
__device__ __forceinline__ short8 readA(const ushort* As, int mi, int k0, int lane)
{
    int r = mi * 16 + (lane & 15);
    int kb = (k0 * 2 + ((lane >> 4) << 4)) ^ ((r & 7) << 4);
    return *(const short8*)((const char*)As + r * 256 + kb);
}

// B-frag from packed weights: b[j] = W[ks*32 + (lane>>4)*8 + j][cc*16 + (lane&15)]
__device__ __forceinline__ short8 readB(const ushort* P, int ks, int NC, int cc,
                                        int laneOff)
{
    return *(const short8*)((const char*)P + (((size_t)(ks * NC + cc)) << 10) + laneOff);
}

// Pack fp32 W[K,N] -> split-bf16 fragment-layout planes Ph, Pl (see readB).
__global__ __launch_bounds__(256) void pack_w2(const float* __restrict__ W,
                                               ushort* __restrict__ Ph,
                                               ushort* __restrict__ Pl, int K, int N)
{
    int NC = N / 16;
    int total = K * N;
    for (int o = blockIdx.x * 256 + threadIdx.x; o < total; o += gridDim.x * 256) {
        int j = o & 7, hi = (o >> 3) & 3, c = (o >> 5) & 15;
        int rest = o >> 9;
        int cc = rest % NC, ks = rest / NC;
        int row = ks * 32 + hi * 8 + j, col = cc * 16 + c;
        float v = W[(size_t)row * N + col];
        ushort h = f2bf(v);
        Ph[o] = h;
        Pl[o] = f2bf(v - bf2f(h));
    }
}

// 3-term split-bf16 MFMA: acc += (ah+al)(bh+bl), dropping lo*lo
#define MFMA3(acc, ah, al, bh, bl)                                              \
    acc = __builtin_amdgcn_mfma_f32_16x16x32_bf16(ah, bh, acc, 0, 0, 0);        \
    acc = __builtin_amdgcn_mfma_f32_16x16x32_bf16(ah, bl, acc, 0, 0, 0);        \
    acc = __builtin_amdgcn_mfma_f32_16x16x32_bf16(al, bh, acc, 0, 0, 0);

// ---------------------------------------------------------------------------
// Fused 2-layer MLP: msg = relu(A@W1+b1)@W2+b2 (fp32 out). 64 rows/block,
// 512 thr (8 waves); wave wv owns output cols [16wv,16wv+16). Hidden in LDS
// as split-bf16.
// ---------------------------------------------------------------------------
__global__ __launch_bounds__(512) void mlp_kernel(
    const float* __restrict__ A,
    const ushort* __restrict__ w1Ph, const ushort* __restrict__ w1Pl,
    const float* __restrict__ b1,
    const ushort* __restrict__ w2Ph, const ushort* __restrict__ w2Pl,
    const float* __restrict__ b2,
    float* __restrict__ msg)
{
    __shared__ __align__(16) ushort AsIn[2 * 64 * 128];
    __shared__ __align__(16) ushort AsHid[2 * 64 * 128];
    const int tid = threadIdx.x;
    const int wv = tid >> 6, lane = tid & 63;
    const int cl = lane & 15, hi = lane >> 4;
    const int rowBase = blockIdx.x * 64;
    const int laneOff = (cl * 4 + hi) * 16;
    const int col = wv * 16 + cl;

    stageA2(A, rowBase, 0, AsIn, tid, 64);
    float b1c = b1[col], b2c = b2[col];
    __syncthreads();

    f32x4 acc[4];
    #pragma unroll
    for (int mi = 0; mi < 4; ++mi) acc[mi] = fzero4();
    #pragma unroll
    for (int ks = 0; ks < 4; ++ks) {
        short8 bh = readB(w1Ph, ks, 8, wv, laneOff);
        short8 bl = readB(w1Pl, ks, 8, wv, laneOff);
        #pragma unroll
        for (int mi = 0; mi < 4; ++mi) {
            short8 ah = readA(AsIn, mi, ks * 32, lane);
            short8 al = readA(AsIn + 64 * 128, mi, ks * 32, lane);
            MFMA3(acc[mi], ah, al, bh, bl);
        }
    }
    #pragma unroll
    for (int mi = 0; mi < 4; ++mi)
        #pragma unroll
        for (int q = 0; q < 4; ++q) {
            int row = mi * 16 + hi * 4 + q;
            float v = fmaxf(acc[mi][q] + b1c, 0.f);
            ushort h = f2bf(v);
            int boff = row * 256 + ((2 * col) ^ ((row & 7) << 4));
            *(ushort*)((char*)AsHid + boff) = h;
            *(ushort*)((char*)AsHid + 64 * 256 + boff) = f2bf(v - bf2f(h));
        }
    __syncthreads();

    f32x4 acc2[4];
    #pragma unroll
    for (int mi = 0; mi < 4; ++mi) acc2[mi] = fzero4();
    #pragma unroll
    for (int ks = 0; ks < 4; ++ks) {
        short8 bh = readB(w2Ph, ks, 8, wv, laneOff);
        short8 bl = readB(w2Pl, ks, 8, wv, laneOff);
        #pragma unroll
        for (int mi = 0; mi < 4; ++mi) {
            short8 ah = readA(AsHid, mi, ks * 32, lane);
            short8 al = readA(AsHid + 64 * 128, mi, ks * 32, lane);
            MFMA3(acc2[mi], ah, al, bh, bl);
        }
    }
    #pragma unroll
    for (int mi = 0; mi < 4; ++mi)
        #pragma unroll
        for (int q = 0; q < 4; ++q) {
            int row = mi * 16 + hi * 4 + q;
            msg[(size_t)(rowBase + row) * DIM + col] = acc2[mi][q] + b2c;
        }
}

// ---------------------------------------------------------------------------
// Edge scatter: aggr[dst[e]][:] += msg[src[e]][:] (fp32). 32 threads/edge,
// 4 dims each (16B gather + 4 fp32 atomics).
// ---------------------------------------------------------------------------
__global__ __launch_bounds__(256) void scatter_kernel(
    const float* __restrict__ msg, const int* __restrict__ src_idx,
    const int* __restrict__ dst_idx, float* __restrict__ aggr)
{
    uint idx = blockIdx.x * 256 + threadIdx.x;   // exactly N_EDGES*32 threads
    int e = idx >> 5, d4 = (idx & 31) << 2;
    int si = src_idx[e], di = dst_idx[e];
    float4 v = *(const float4*)(msg + (size_t)si * DIM + d4);
    float* a = aggr + (size_t)di * DIM + d4;
    atomicAdd(a + 0, v.x);
    atomicAdd(a + 1, v.y);
    atomicAdd(a + 2, v.z);
    atomicAdd(a + 3, v.w);
}

// ---------------------------------------------------------------------------
// Fused LN-LSTM cell. 32 rows/block, 512 threads = 8 waves.
// Wave wv owns gate cols {128*jb + 16*wv + cl : jb=0..3}: per (row,d) the four
// gates i,f,g,o live in the SAME lane. X = X0@wi[0:128] (+ X1^xor@wi[128:256]
// when KX==8), Hg = Hsrc@wh. All GEMMs split-bf16 (3x MFMA). LN(512) via
// 16-lane shfl + cross-wave LDS reduce; LN(128) on new_c the same way.
// ---------------------------------------------------------------------------
template<int KX>   // 4 = clause (K_x=128), 8 = literal (K_x=256, X1 flip rows)
__global__ __launch_bounds__(512) void lstm_kernel(
    const float* __restrict__ X0, const float* __restrict__ X1, int xor1,
    const float* __restrict__ Hsrc,
    const ushort* __restrict__ wiPh, const ushort* __restrict__ wiPl,
    const ushort* __restrict__ whPh, const ushort* __restrict__ whPl,
    const float* __restrict__ g_ih, const float* __restrict__ b_ih,
    const float* __restrict__ g_hh, const float* __restrict__ b_hh,
    const float* __restrict__ g_c,  const float* __restrict__ b_c,
    float* __restrict__ c_state, float* __restrict__ h_out)
{
    __shared__ __align__(16) ushort AsX0[2 * 32 * 128];
    __shared__ __align__(16) ushort AsX1[KX == 8 ? 2 * 32 * 128 : 8];
    __shared__ __align__(16) ushort AsH [2 * 32 * 128];
    __shared__ float red4[32][8][4];
    __shared__ float lnst[32][4];
    __shared__ float red2[32][8][2];
    __shared__ float lnc[32][2];

    const int tid = threadIdx.x;
    const int wv = tid >> 6, lane = tid & 63;
    const int cl = lane & 15, hi = lane >> 4;
    const int rowBase = blockIdx.x * 32;
    const int laneOff = (cl * 4 + hi) * 16;
    const int d = wv * 16 + cl;

    stageA2(X0, rowBase, 0, AsX0, tid, 32);
    if (KX == 8) stageA2(X1, rowBase, xor1, AsX1, tid, 32);
    stageA2(Hsrc, rowBase, 0, AsH, tid, 32);

    float gih[4], bih[4], ghh[4], bhh[4];
    #pragma unroll
    for (int jb = 0; jb < 4; ++jb) {
        int col = jb * 128 + d;
        gih[jb] = g_ih[col]; bih[jb] = b_ih[col];
        ghh[jb] = g_hh[col]; bhh[jb] = b_hh[col];
    }
    const float gcv = g_c[d], bcv = b_c[d];

    __syncthreads();

    f32x4 xacc[2][4], hacc[2][4];
    #pragma unroll
    for (int mi = 0; mi < 2; ++mi)
        #pragma unroll
        for (int jb = 0; jb < 4; ++jb) { xacc[mi][jb] = fzero4(); hacc[mi][jb] = fzero4(); }

    #pragma unroll
    for (int ks = 0; ks < KX; ++ks) {
        const ushort* AX = (KX == 8 && ks >= 4) ? AsX1 : AsX0;
        int k0 = (ks & 3) * 32;
        short8 axh0 = readA(AX, 0, k0, lane);
        short8 axl0 = readA(AX + 32 * 128, 0, k0, lane);
        short8 axh1 = readA(AX, 1, k0, lane);
        short8 axl1 = readA(AX + 32 * 128, 1, k0, lane);
        #pragma unroll
        for (int jb = 0; jb < 4; ++jb) {
            short8 bh = readB(wiPh, ks, 32, jb * 8 + wv, laneOff);
            short8 bl = readB(wiPl, ks, 32, jb * 8 + wv, laneOff);
            MFMA3(xacc[0][jb], axh0, axl0, bh, bl);
            MFMA3(xacc[1][jb], axh1, axl1, bh, bl);
        }
        if (ks < 4) {
            short8 ahh0 = readA(AsH, 0, k0, lane);
            short8 ahl0 = readA(AsH + 32 * 128, 0, k0, lane);
            short8 ahh1 = readA(AsH, 1, k0, lane);
            short8 ahl1 = readA(AsH + 32 * 128, 1, k0, lane);
            #pragma unroll
            for (int jb = 0; jb < 4; ++jb) {
                short8 bh = readB(whPh, ks, 32, jb * 8 + wv, laneOff);
                short8 bl = readB(whPl, ks, 32, jb * 8 + wv, laneOff);
                MFMA3(hacc[0][jb], ahh0, ahl0, bh, bl);
                MFMA3(hacc[1][jb], ahh1, ahl1, bh, bl);
            }
        }
    }

    // ---- LN(512) stats for X and H ----
    #pragma unroll
    for (int mi = 0; mi < 2; ++mi)
        #pragma unroll
        for (int q = 0; q < 4; ++q) {
            float px = 0.f, pqx = 0.f, ph = 0.f, pqh = 0.f;
            #pragma unroll
            for (int jb = 0; jb < 4; ++jb) {
                float v = xacc[mi][jb][q]; px += v; pqx += v * v;
                float u = hacc[mi][jb][q]; ph += u; pqh += u * u;
            }
            #pragma unroll
            for (int m = 1; m < 16; m <<= 1) {
                px += __shfl_xor(px, m); pqx += __shfl_xor(pqx, m);
                ph += __shfl_xor(ph, m); pqh += __shfl_xor(pqh, m);
            }
            if (cl == 0) {
                int row = mi * 16 + hi * 4 + q;
                red4[row][wv][0] = px; red4[row][wv][1] = pqx;
                red4[row][wv][2] = ph; red4[row][wv][3] = pqh;
            }
        }
    __syncthreads();
    if (tid < 32) {
        float sx = 0.f, qx = 0.f, sh = 0.f, qh = 0.f;
        for (int ww = 0; ww < 8; ++ww) {
            sx += red4[tid][ww][0]; qx += red4[tid][ww][1];
            sh += red4[tid][ww][2]; qh += red4[tid][ww][3];
        }
        const float inv = 1.f / 512.f;
        float mux = sx * inv, muh = sh * inv;
        lnst[tid][0] = mux; lnst[tid][1] = rsqrtf(qx * inv - mux * mux + 1e-5f);
        lnst[tid][2] = muh; lnst[tid][3] = rsqrtf(qh * inv - muh * muh + 1e-5f);
    }
    __syncthreads();

    // ---- gates -> new_c, stash o-gate; LN(128) stats on new_c ----
    float cn[2][4], og[2][4];
    #pragma unroll
    for (int mi = 0; mi < 2; ++mi)
        #pragma unroll
        for (int q = 0; q < 4; ++q) {
            int row = mi * 16 + hi * 4 + q;
            float mux = lnst[row][0], rx = lnst[row][1];
            float muh = lnst[row][2], rh = lnst[row][3];
            float g4[4];
            #pragma unroll
            for (int jb = 0; jb < 4; ++jb)
                g4[jb] = (xacc[mi][jb][q] - mux) * rx * gih[jb] + bih[jb]
                       + (hacc[mi][jb][q] - muh) * rh * ghh[jb] + bhh[jb];
            float cp = c_state[(size_t)(rowBase + row) * DIM + d];
            float cv = sigmf(g4[1]) * cp + sigmf(g4[0]) * tanh_f(g4[2]);
            cn[mi][q] = cv; og[mi][q] = g4[3];
            float sc = cv, qc = cv * cv;
            #pragma unroll
            for (int m = 1; m < 16; m <<= 1) {
                sc += __shfl_xor(sc, m); qc += __shfl_xor(qc, m);
            }
            if (cl == 0) { red2[row][wv][0] = sc; red2[row][wv][1] = qc; }
        }
    __syncthreads();
    if (tid < 32) {
        float sc = 0.f, qc = 0.f;
        for (int ww = 0; ww < 8; ++ww) { sc += red2[tid][ww][0]; qc += red2[tid][ww][1]; }
        const float inv = 1.f / 128.f;
        float mu = sc * inv;
        lnc[tid][0] = mu; lnc[tid][1] = rsqrtf(qc * inv - mu * mu + 1e-5f);
    }
    __syncthreads();

    #pragma unroll
    for (int mi = 0; mi < 2; ++mi)
        #pragma unroll
        for (int q = 0; q < 4; ++q) {
            int row = mi * 16 + hi * 4 + q;
            size_t go = (size_t)(rowBase + row) * DIM + d;
            float cv = cn[mi][q];
            float hv = sigmf(og[mi][q]) *
                       tanh_f((cv - lnc[row][0]) * lnc[row][1] * gcv + bcv);
            c_state[go] = cv;
            h_out[go] = hv;
        }
}

// ---------------------------------------------------------------------------
extern "C" void kernel_launch(void* const* d_in, const int* in_sizes, int n_in,
                              void* d_out, int out_size, void* d_ws, size_t ws_size,
                              hipStream_t stream)
{
    const int*   l_edge  = (const int*)d_in[2];
    const int*   c_edge  = (const int*)d_in[3];
    const float* l_emb0  = (const float*)d_in[4];
    const float* c_emb0  = (const float*)d_in[5];
    const float* l2c_w1  = (const float*)d_in[6];
    const float* l2c_b1  = (const float*)d_in[7];
    const float* l2c_w2  = (const float*)d_in[8];
    const float* l2c_b2  = (const float*)d_in[9];
    const float* c2l_w1  = (const float*)d_in[10];
    const float* c2l_b1  = (const float*)d_in[11];
    const float* c2l_w2  = (const float*)d_in[12];
    const float* c2l_b2  = (const float*)d_in[13];
    const float* cu_wi   = (const float*)d_in[14];
    const float* cu_wh   = (const float*)d_in[15];
    const float* cu_g_ih = (const float*)d_in[16];
    const float* cu_b_ih = (const float*)d_in[17];
    const float* cu_g_hh = (const float*)d_in[18];
    const float* cu_b_hh = (const float*)d_in[19];
    const float* cu_g_c  = (const float*)d_in[20];
    const float* cu_b_c  = (const float*)d_in[21];
    const float* lu_wi   = (const float*)d_in[22];
    const float* lu_wh   = (const float*)d_in[23];
    const float* lu_g_ih = (const float*)d_in[24];
    const float* lu_b_ih = (const float*)d_in[25];
    const float* lu_g_hh = (const float*)d_in[26];
    const float* lu_b_hh = (const float*)d_in[27];
    const float* lu_g_c  = (const float*)d_in[28];
    const float* lu_b_c  = (const float*)d_in[29];

    float* out = (float*)d_out;
    float* l_slab = out;                              // [9, L, 128]
    float* c_slab = out + (size_t)9 * L_SIZE * DIM;   // [9, C, 128]

    // ---- workspace (~227 MB; round-2 layout already proved >= 225 MB ok) ----
    char* wp = (char*)d_ws;
    float*  l_state = (float*)wp;  wp += (size_t)L_SIZE * DIM * 4;   // 41.0 MB
    float*  c_state = (float*)wp;  wp += (size_t)C_SIZE * DIM * 4;   // 61.4 MB
    float*  aggr    = (float*)wp;  wp += (size_t)C_SIZE * DIM * 4;   // 61.4 MB
    float*  msg     = (float*)wp;  wp += (size_t)C_SIZE * DIM * 4;   // 61.4 MB
    ushort* l2c_w1Ph = (ushort*)wp; wp += 128 * 128 * 2;
    ushort* l2c_w1Pl = (ushort*)wp; wp += 128 * 128 * 2;
    ushort* l2c_w2Ph = (ushort*)wp; wp += 128 * 128 * 2;
    ushort* l2c_w2Pl = (ushort*)wp; wp += 128 * 128 * 2;
    ushort* c2l_w1Ph = (ushort*)wp; wp += 128 * 128 * 2;
    ushort* c2l_w1Pl = (ushort*)wp; wp += 128 * 128 * 2;
    ushort* c2l_w2Ph = (ushort*)wp; wp += 128 * 128 * 2;
    ushort* c2l_w2Pl = (ushort*)wp; wp += 128 * 128 * 2;
    ushort* cu_wiPh  = (ushort*)wp; wp += 128 * 512 * 2;
    ushort* cu_wiPl  = (ushort*)wp; wp += 128 * 512 * 2;
    ushort* cu_whPh  = (ushort*)wp; wp += 128 * 512 * 2;
    ushort* cu_whPl  = (ushort*)wp; wp += 128 * 512 * 2;
    ushort* lu_wiPh  = (ushort*)wp; wp += 256 * 512 * 2;
    ushort* lu_wiPl  = (ushort*)wp; wp += 256 * 512 * 2;
    ushort* lu_whPh  = (ushort*)wp; wp += 128 * 512 * 2;
    ushort* lu_whPl  = (ushort*)wp; wp += 128 * 512 * 2;

    // pack weights to split-bf16 fragment layout (re-done every call)
    pack_w2<<<64, 256, 0, stream>>>(l2c_w1, l2c_w1Ph, l2c_w1Pl, 128, 128);
    pack_w2<<<64, 256, 0, stream>>>(l2c_w2, l2c_w2Ph, l2c_w2Pl, 128, 128);
    pack_w2<<<64, 256, 0, stream>>>(c2l_w1, c2l_w1Ph, c2l_w1Pl, 128, 128);
    pack_w2<<<64, 256, 0, stream>>>(c2l_w2, c2l_w2Ph, c2l_w2Pl, 128, 128);
    pack_w2<<<256, 256, 0, stream>>>(cu_wi, cu_wiPh, cu_wiPl, 128, 512);
    pack_w2<<<256, 256, 0, stream>>>(cu_wh, cu_whPh, cu_whPl, 128, 512);
    pack_w2<<<512, 256, 0, stream>>>(lu_wi, lu_wiPh, lu_wiPl, 256, 512);
    pack_w2<<<256, 256, 0, stream>>>(lu_wh, lu_whPh, lu_whPl, 128, 512);

    hipMemcpyAsync(l_slab, l_emb0, (size_t)L_SIZE * DIM * sizeof(float),
                   hipMemcpyDeviceToDevice, stream);
    hipMemcpyAsync(c_slab, c_emb0, (size_t)C_SIZE * DIM * sizeof(float),
                   hipMemcpyDeviceToDevice, stream);
    hipMemsetAsync(l_state, 0, (size_t)L_SIZE * DIM * sizeof(float), stream);
    hipMemsetAsync(c_state, 0, (size_t)C_SIZE * DIM * sizeof(float), stream);

    const int scat_blocks = (N_EDGES * 32) / 256;   // 60000

    for (int t = 0; t < N_ITER; ++t) {
        const float* le = l_slab + (size_t)t * L_SIZE * DIM;
        const float* ce = c_slab + (size_t)t * C_SIZE * DIM;
        float* le1 = l_slab + (size_t)(t + 1) * L_SIZE * DIM;
        float* ce1 = c_slab + (size_t)(t + 1) * C_SIZE * DIM;

        // ---- literal -> clause ----
        mlp_kernel<<<L_SIZE / 64, 512, 0, stream>>>(le, l2c_w1Ph, l2c_w1Pl, l2c_b1,
                                                    l2c_w2Ph, l2c_w2Pl, l2c_b2, msg);
        hipMemsetAsync(aggr, 0, (size_t)C_SIZE * DIM * sizeof(float), stream);
        scatter_kernel<<<scat_blocks, 256, 0, stream>>>(msg, l_edge, c_edge, aggr);
        lstm_kernel<4><<<C_SIZE / 32, 512, 0, stream>>>(
            aggr, nullptr, 0, ce, cu_wiPh, cu_wiPl, cu_whPh, cu_whPl,
            cu_g_ih, cu_b_ih, cu_g_hh, cu_b_hh, cu_g_c, cu_b_c,
            c_state, ce1);

        // ---- clause -> literal ----
        mlp_kernel<<<C_SIZE / 64, 512, 0, stream>>>(ce1, c2l_w1Ph, c2l_w1Pl, c2l_b1,
                                                    c2l_w2Ph, c2l_w2Pl, c2l_b2, msg);
        hipMemsetAsync(aggr, 0, (size_t)L_SIZE * DIM * sizeof(float), stream);
        scatter_kernel<<<scat_blocks, 256, 0, stream>>>(msg, c_edge, l_edge, aggr);
        lstm_kernel<8><<<L_SIZE / 32, 512, 0, stream>>>(
            aggr, le, 1, le, lu_wiPh, lu_wiPl, lu_whPh, lu_whPl,
            lu_g_ih, lu_b_ih, lu_g_hh, lu_b_hh, lu_g_c, lu_b_c,
            l_state, le1);
    }
}

// Round 5
// 6142.161 us; speedup vs baseline: 2.9287x; 2.9287x over previous
//
#include <hip/hip_runtime.h>
#include <hip/hip_bf16.h>

#define L_SIZE 80000
#define C_SIZE 120000
#define N_EDGES 480000
#define DIM 128
#define GDIM 512
#define N_ITER 8

typedef __attribute__((ext_vector_type(8))) short short8;   // 8 bf16 (4 VGPR) MFMA frag
typedef __attribute__((ext_vector_type(4))) float f32x4;    // MFMA acc frag

__device__ __forceinline__ ushort f2bf(float f) {           // fp32 -> bf16 RNE
    uint u = __float_as_uint(f);
    u = u + 0x7FFFu + ((u >> 16) & 1u);
    return (ushort)(u >> 16);
}
__device__ __forceinline__ float bf2f(ushort h) {
    return __uint_as_float(((uint)h) << 16);
}
__device__ __forceinline__ float sigmf(float x) { return 1.f / (1.f + __expf(-x)); }
__device__ __forceinline__ float tanh_f(float x) {
    float e = __expf(2.f * x);
    return 1.f - 2.f / (e + 1.f);
}
__device__ __forceinline__ f32x4 fzero4() {
    f32x4 v; v[0] = v[1] = v[2] = v[3] = 0.f; return v;
}

// ---------------------------------------------------------------------------
// CSR build: counts -> exclusive offsets -> slot fill (src row id per slot).
// Rebuilt identically every call (edge lists are inputs). Data-path has no
// atomics afterwards; slot order nondeterminism only permutes fp32 sum order.
// ---------------------------------------------------------------------------
__global__ __launch_bounds__(256) void count_kernel(
    const int* __restrict__ dst, int* __restrict__ counts)
{
    int i = blockIdx.x * 256 + threadIdx.x;      // grid sized exactly N_EDGES/256
    atomicAdd(&counts[dst[i]], 1);
}

// Single-block exclusive scan of counts[n] -> offsets[n+1].
__global__ __launch_bounds__(1024) void scan_kernel(
    const int* __restrict__ counts, int* __restrict__ offsets, int n)
{
    __shared__ int psum[1024];
    const int tid = threadIdx.x;
    const int chunk = (n + 1023) / 1024;
    int lo = tid * chunk, hi = lo + chunk; if (hi > n) hi = n;
    int s = 0;
    for (int i = lo; i < hi; ++i) s += counts[i];
    psum[tid] = s;
    __syncthreads();
    for (int off = 1; off < 1024; off <<= 1) {   // Hillis-Steele inclusive
        int v = (tid >= off) ? psum[tid - off] : 0;
        __syncthreads();
        psum[tid] += v;
        __syncthreads();
    }
    int run = tid ? psum[tid - 1] : 0;           // exclusive base for this chunk
    for (int i = lo; i < hi; ++i) { offsets[i] = run; run += counts[i]; }
    if (tid == 1023) offsets[n] = run;           // total
}

__global__ __launch_bounds__(256) void fill_kernel(
    const int* __restrict__ src, const int* __restrict__ dst,
    int* __restrict__ cursor, int* __restrict__ srclist)
{
    int i = blockIdx.x * 256 + threadIdx.x;      // grid sized exactly N_EDGES/256
    int d = dst[i];
    int pos = atomicAdd(&cursor[d], 1);
    srclist[pos] = src[i];
}

// ---------------------------------------------------------------------------
// Gather aggregation: aggr[r][:] = sum_{p in [off[r],off[r+1])} msg[srclist[p]][:]
// 8 rows/block, 32 threads/row, float4 per thread. No atomics.
// ---------------------------------------------------------------------------
__global__ __launch_bounds__(256) void aggregate_kernel(
    const float* __restrict__ msg, const int* __restrict__ offsets,
    const int* __restrict__ srclist, float* __restrict__ aggr, int nrows)
{
    int row = blockIdx.x * 8 + (threadIdx.x >> 5);
    if (row >= nrows) return;
    int d4 = (threadIdx.x & 31) << 2;
    int s = offsets[row], e = offsets[row + 1];
    float4 acc = {0.f, 0.f, 0.f, 0.f};
    for (int p = s; p < e; ++p) {
        int sr = srclist[p];
        float4 v = *(const float4*)(msg + (size_t)sr * DIM + d4);
        acc.x += v.x; acc.y += v.y; acc.z += v.z; acc.w += v.w;
    }
    *(float4*)(aggr + (size_t)row * DIM + d4) = acc;
}

// ---------------------------------------------------------------------------
// Stage fp32 [nrows,128] rows (rowBase..)^rowXor into LDS as TWO bf16 planes:
// hi at dst, lo at dst + nrows*128 (split-bf16: v = hi + lo + O(2^-17 v)).
// Row stride 256B, XOR-swizzled: byte ^= (row&7)<<4 (conflict-free b128 reads).
// ---------------------------------------------------------------------------
__device__ __forceinline__ void stageA2(const float* __restrict__ src, int rowBase,
                                        int rowXor, ushort* dst, int tid, int nrows)
{
    const int planeB = nrows * 256;   // bytes per plane
    for (int idx = tid * 8; idx < nrows * 128; idx += 512 * 8) {
        int r = idx >> 7, k8 = idx & 127;
        const float* p = src + (size_t)((rowBase + r) ^ rowXor) * DIM + k8;
        float4 v0 = *(const float4*)p;
        float4 v1 = *(const float4*)(p + 4);
        float f[8] = {v0.x, v0.y, v0.z, v0.w, v1.x, v1.y, v1.z, v1.w};
        short8 hi, lo;
        #pragma unroll
        for (int j = 0; j < 8; ++j) {
            ushort h = f2bf(f[j]);
            hi[j] = (short)h;
            lo[j] = (short)f2bf(f[j] - bf2f(h));
        }
        int boff = r * 256 + ((k8 * 2) ^ ((r & 7) << 4));
        *(short8*)((char*)dst + boff) = hi;
        *(short8*)((char*)dst + planeB + boff) = lo;
    }
}

// A-frag: a[j] = A[mi*16 + (lane&15)][k0 + (lane>>4)*8 + j]  (swizzled LDS plane)
__device__ __forceinline__ short8 readA(const ushort* As, int mi, int k0, int lane)
{
    int r = mi * 16 + (lane & 15);
    int kb = (k0 * 2 + ((lane >> 4) << 4)) ^ ((r & 7) << 4);
    return *(const short8*)((const char*)As + r * 256 + kb);
}

// B-frag from packed weights: b[j] = W[ks*32 + (lane>>4)*8 + j][cc*16 + (lane&15)]
__device__ __forceinline__ short8 readB(const ushort* P, int ks, int NC, int cc,
                                        int laneOff)
{
    return *(const short8*)((const char*)P + (((size_t)(ks * NC + cc)) << 10) + laneOff);
}

// Pack fp32 W[K,N] -> split-bf16 fragment-layout planes Ph, Pl (see readB).
__global__ __launch_bounds__(256) void pack_w2(const float* __restrict__ W,
                                               ushort* __restrict__ Ph,
                                               ushort* __restrict__ Pl, int K, int N)
{
    int NC = N / 16;
    int total = K * N;
    for (int o = blockIdx.x * 256 + threadIdx.x; o < total; o += gridDim.x * 256) {
        int j = o & 7, hi = (o >> 3) & 3, c = (o >> 5) & 15;
        int rest = o >> 9;
        int cc = rest % NC, ks = rest / NC;
        int row = ks * 32 + hi * 8 + j, col = cc * 16 + c;
        float v = W[(size_t)row * N + col];
        ushort h = f2bf(v);
        Ph[o] = h;
        Pl[o] = f2bf(v - bf2f(h));
    }
}

// 3-term split-bf16 MFMA: acc += (ah+al)(bh+bl), dropping lo*lo
#define MFMA3(acc, ah, al, bh, bl)                                              \
    acc = __builtin_amdgcn_mfma_f32_16x16x32_bf16(ah, bh, acc, 0, 0, 0);        \
    acc = __builtin_amdgcn_mfma_f32_16x16x32_bf16(ah, bl, acc, 0, 0, 0);        \
    acc = __builtin_amdgcn_mfma_f32_16x16x32_bf16(al, bh, acc, 0, 0, 0);

// ---------------------------------------------------------------------------
// Fused 2-layer MLP: msg = relu(A@W1+b1)@W2+b2 (fp32 out). 64 rows/block,
// 512 thr (8 waves); wave wv owns output cols [16wv,16wv+16). Hidden in LDS
// as split-bf16.
// ---------------------------------------------------------------------------
__global__ __launch_bounds__(512) void mlp_kernel(
    const float* __restrict__ A,
    const ushort* __restrict__ w1Ph, const ushort* __restrict__ w1Pl,
    const float* __restrict__ b1,
    const ushort* __restrict__ w2Ph, const ushort* __restrict__ w2Pl,
    const float* __restrict__ b2,
    float* __restrict__ msg)
{
    __shared__ __align__(16) ushort AsIn[2 * 64 * 128];
    __shared__ __align__(16) ushort AsHid[2 * 64 * 128];
    const int tid = threadIdx.x;
    const int wv = tid >> 6, lane = tid & 63;
    const int cl = lane & 15, hi = lane >> 4;
    const int rowBase = blockIdx.x * 64;
    const int laneOff = (cl * 4 + hi) * 16;
    const int col = wv * 16 + cl;

    stageA2(A, rowBase, 0, AsIn, tid, 64);
    float b1c = b1[col], b2c = b2[col];
    __syncthreads();

    f32x4 acc[4];
    #pragma unroll
    for (int mi = 0; mi < 4; ++mi) acc[mi] = fzero4();
    #pragma unroll
    for (int ks = 0; ks < 4; ++ks) {
        short8 bh = readB(w1Ph, ks, 8, wv, laneOff);
        short8 bl = readB(w1Pl, ks, 8, wv, laneOff);
        #pragma unroll
        for (int mi = 0; mi < 4; ++mi) {
            short8 ah = readA(AsIn, mi, ks * 32, lane);
            short8 al = readA(AsIn + 64 * 128, mi, ks * 32, lane);
            MFMA3(acc[mi], ah, al, bh, bl);
        }
    }
    #pragma unroll
    for (int mi = 0; mi < 4; ++mi)
        #pragma unroll
        for (int q = 0; q < 4; ++q) {
            int row = mi * 16 + hi * 4 + q;
            float v = fmaxf(acc[mi][q] + b1c, 0.f);
            ushort h = f2bf(v);
            int boff = row * 256 + ((2 * col) ^ ((row & 7) << 4));
            *(ushort*)((char*)AsHid + boff) = h;
            *(ushort*)((char*)AsHid + 64 * 256 + boff) = f2bf(v - bf2f(h));
        }
    __syncthreads();

    f32x4 acc2[4];
    #pragma unroll
    for (int mi = 0; mi < 4; ++mi) acc2[mi] = fzero4();
    #pragma unroll
    for (int ks = 0; ks < 4; ++ks) {
        short8 bh = readB(w2Ph, ks, 8, wv, laneOff);
        short8 bl = readB(w2Pl, ks, 8, wv, laneOff);
        #pragma unroll
        for (int mi = 0; mi < 4; ++mi) {
            short8 ah = readA(AsHid, mi, ks * 32, lane);
            short8 al = readA(AsHid + 64 * 128, mi, ks * 32, lane);
            MFMA3(acc2[mi], ah, al, bh, bl);
        }
    }
    #pragma unroll
    for (int mi = 0; mi < 4; ++mi)
        #pragma unroll
        for (int q = 0; q < 4; ++q) {
            int row = mi * 16 + hi * 4 + q;
            msg[(size_t)(rowBase + row) * DIM + col] = acc2[mi][q] + b2c;
        }
}

// ---------------------------------------------------------------------------
// Fused LN-LSTM cell. 32 rows/block, 512 threads = 8 waves.
// Wave wv owns gate cols {128*jb + 16*wv + cl : jb=0..3}: per (row,d) the four
// gates i,f,g,o live in the SAME lane. X = X0@wi[0:128] (+ X1^xor@wi[128:256]
// when KX==8), Hg = Hsrc@wh. All GEMMs split-bf16 (3x MFMA). LN(512) via
// 16-lane shfl + cross-wave LDS reduce; LN(128) on new_c the same way.
// ---------------------------------------------------------------------------
template<int KX>   // 4 = clause (K_x=128), 8 = literal (K_x=256, X1 flip rows)
__global__ __launch_bounds__(512) void lstm_kernel(
    const float* __restrict__ X0, const float* __restrict__ X1, int xor1,
    const float* __restrict__ Hsrc,
    const ushort* __restrict__ wiPh, const ushort* __restrict__ wiPl,
    const ushort* __restrict__ whPh, const ushort* __restrict__ whPl,
    const float* __restrict__ g_ih, const float* __restrict__ b_ih,
    const float* __restrict__ g_hh, const float* __restrict__ b_hh,
    const float* __restrict__ g_c,  const float* __restrict__ b_c,
    float* __restrict__ c_state, float* __restrict__ h_out)
{
    __shared__ __align__(16) ushort AsX0[2 * 32 * 128];
    __shared__ __align__(16) ushort AsX1[KX == 8 ? 2 * 32 * 128 : 8];
    __shared__ __align__(16) ushort AsH [2 * 32 * 128];
    __shared__ float red4[32][8][4];
    __shared__ float lnst[32][4];
    __shared__ float red2[32][8][2];
    __shared__ float lnc[32][2];

    const int tid = threadIdx.x;
    const int wv = tid >> 6, lane = tid & 63;
    const int cl = lane & 15, hi = lane >> 4;
    const int rowBase = blockIdx.x * 32;
    const int laneOff = (cl * 4 + hi) * 16;
    const int d = wv * 16 + cl;

    stageA2(X0, rowBase, 0, AsX0, tid, 32);
    if (KX == 8) stageA2(X1, rowBase, xor1, AsX1, tid, 32);
    stageA2(Hsrc, rowBase, 0, AsH, tid, 32);

    float gih[4], bih[4], ghh[4], bhh[4];
    #pragma unroll
    for (int jb = 0; jb < 4; ++jb) {
        int col = jb * 128 + d;
        gih[jb] = g_ih[col]; bih[jb] = b_ih[col];
        ghh[jb] = g_hh[col]; bhh[jb] = b_hh[col];
    }
    const float gcv = g_c[d], bcv = b_c[d];

    __syncthreads();

    f32x4 xacc[2][4], hacc[2][4];
    #pragma unroll
    for (int mi = 0; mi < 2; ++mi)
        #pragma unroll
        for (int jb = 0; jb < 4; ++jb) { xacc[mi][jb] = fzero4(); hacc[mi][jb] = fzero4(); }

    #pragma unroll
    for (int ks = 0; ks < KX; ++ks) {
        const ushort* AX = (KX == 8 && ks >= 4) ? AsX1 : AsX0;
        int k0 = (ks & 3) * 32;
        short8 axh0 = readA(AX, 0, k0, lane);
        short8 axl0 = readA(AX + 32 * 128, 0, k0, lane);
        short8 axh1 = readA(AX, 1, k0, lane);
        short8 axl1 = readA(AX + 32 * 128, 1, k0, lane);
        #pragma unroll
        for (int jb = 0; jb < 4; ++jb) {
            short8 bh = readB(wiPh, ks, 32, jb * 8 + wv, laneOff);
            short8 bl = readB(wiPl, ks, 32, jb * 8 + wv, laneOff);
            MFMA3(xacc[0][jb], axh0, axl0, bh, bl);
            MFMA3(xacc[1][jb], axh1, axl1, bh, bl);
        }
        if (ks < 4) {
            short8 ahh0 = readA(AsH, 0, k0, lane);
            short8 ahl0 = readA(AsH + 32 * 128, 0, k0, lane);
            short8 ahh1 = readA(AsH, 1, k0, lane);
            short8 ahl1 = readA(AsH + 32 * 128, 1, k0, lane);
            #pragma unroll
            for (int jb = 0; jb < 4; ++jb) {
                short8 bh = readB(whPh, ks, 32, jb * 8 + wv, laneOff);
                short8 bl = readB(whPl, ks, 32, jb * 8 + wv, laneOff);
                MFMA3(hacc[0][jb], ahh0, ahl0, bh, bl);
                MFMA3(hacc[1][jb], ahh1, ahl1, bh, bl);
            }
        }
    }

    // ---- LN(512) stats for X and H ----
    #pragma unroll
    for (int mi = 0; mi < 2; ++mi)
        #pragma unroll
        for (int q = 0; q < 4; ++q) {
            float px = 0.f, pqx = 0.f, ph = 0.f, pqh = 0.f;
            #pragma unroll
            for (int jb = 0; jb < 4; ++jb) {
                float v = xacc[mi][jb][q]; px += v; pqx += v * v;
                float u = hacc[mi][jb][q]; ph += u; pqh += u * u;
            }
            #pragma unroll
            for (int m = 1; m < 16; m <<= 1) {
                px += __shfl_xor(px, m); pqx += __shfl_xor(pqx, m);
                ph += __shfl_xor(ph, m); pqh += __shfl_xor(pqh, m);
            }
            if (cl == 0) {
                int row = mi * 16 + hi * 4 + q;
                red4[row][wv][0] = px; red4[row][wv][1] = pqx;
                red4[row][wv][2] = ph; red4[row][wv][3] = pqh;
            }
        }
    __syncthreads();
    if (tid < 32) {
        float sx = 0.f, qx = 0.f, sh = 0.f, qh = 0.f;
        for (int ww = 0; ww < 8; ++ww) {
            sx += red4[tid][ww][0]; qx += red4[tid][ww][1];
            sh += red4[tid][ww][2]; qh += red4[tid][ww][3];
        }
        const float inv = 1.f / 512.f;
        float mux = sx * inv, muh = sh * inv;
        lnst[tid][0] = mux; lnst[tid][1] = rsqrtf(qx * inv - mux * mux + 1e-5f);
        lnst[tid][2] = muh; lnst[tid][3] = rsqrtf(qh * inv - muh * muh + 1e-5f);
    }
    __syncthreads();

    // ---- gates -> new_c, stash o-gate; LN(128) stats on new_c ----
    float cn[2][4], og[2][4];
    #pragma unroll
    for (int mi = 0; mi < 2; ++mi)
        #pragma unroll
        for (int q = 0; q < 4; ++q) {
            int row = mi * 16 + hi * 4 + q;
            float mux = lnst[row][0], rx = lnst[row][1];
            float muh = lnst[row][2], rh = lnst[row][3];
            float g4[4];
            #pragma unroll
            for (int jb = 0; jb < 4; ++jb)
                g4[jb] = (xacc[mi][jb][q] - mux) * rx * gih[jb] + bih[jb]
                       + (hacc[mi][jb][q] - muh) * rh * ghh[jb] + bhh[jb];
            float cp = c_state[(size_t)(rowBase + row) * DIM + d];
            float cv = sigmf(g4[1]) * cp + sigmf(g4[0]) * tanh_f(g4[2]);
            cn[mi][q] = cv; og[mi][q] = g4[3];
            float sc = cv, qc = cv * cv;
            #pragma unroll
            for (int m = 1; m < 16; m <<= 1) {
                sc += __shfl_xor(sc, m); qc += __shfl_xor(qc, m);
            }
            if (cl == 0) { red2[row][wv][0] = sc; red2[row][wv][1] = qc; }
        }
    __syncthreads();
    if (tid < 32) {
        float sc = 0.f, qc = 0.f;
        for (int ww = 0; ww < 8; ++ww) { sc += red2[tid][ww][0]; qc += red2[tid][ww][1]; }
        const float inv = 1.f / 128.f;
        float mu = sc * inv;
        lnc[tid][0] = mu; lnc[tid][1] = rsqrtf(qc * inv - mu * mu + 1e-5f);
    }
    __syncthreads();

    #pragma unroll
    for (int mi = 0; mi < 2; ++mi)
        #pragma unroll
        for (int q = 0; q < 4; ++q) {
            int row = mi * 16 + hi * 4 + q;
            size_t go = (size_t)(rowBase + row) * DIM + d;
            float cv = cn[mi][q];
            float hv = sigmf(og[mi][q]) *
                       tanh_f((cv - lnc[row][0]) * lnc[row][1] * gcv + bcv);
            c_state[go] = cv;
            h_out[go] = hv;
        }
}

// ---------------------------------------------------------------------------
extern "C" void kernel_launch(void* const* d_in, const int* in_sizes, int n_in,
                              void* d_out, int out_size, void* d_ws, size_t ws_size,
                              hipStream_t stream)
{
    const int*   l_edge  = (const int*)d_in[2];
    const int*   c_edge  = (const int*)d_in[3];
    const float* l_emb0  = (const float*)d_in[4];
    const float* c_emb0  = (const float*)d_in[5];
    const float* l2c_w1  = (const float*)d_in[6];
    const float* l2c_b1  = (const float*)d_in[7];
    const float* l2c_w2  = (const float*)d_in[8];
    const float* l2c_b2  = (const float*)d_in[9];
    const float* c2l_w1  = (const float*)d_in[10];
    const float* c2l_b1  = (const float*)d_in[11];
    const float* c2l_w2  = (const float*)d_in[12];
    const float* c2l_b2  = (const float*)d_in[13];
    const float* cu_wi   = (const float*)d_in[14];
    const float* cu_wh   = (const float*)d_in[15];
    const float* cu_g_ih = (const float*)d_in[16];
    const float* cu_b_ih = (const float*)d_in[17];
    const float* cu_g_hh = (const float*)d_in[18];
    const float* cu_b_hh = (const float*)d_in[19];
    const float* cu_g_c  = (const float*)d_in[20];
    const float* cu_b_c  = (const float*)d_in[21];
    const float* lu_wi   = (const float*)d_in[22];
    const float* lu_wh   = (const float*)d_in[23];
    const float* lu_g_ih = (const float*)d_in[24];
    const float* lu_b_ih = (const float*)d_in[25];
    const float* lu_g_hh = (const float*)d_in[26];
    const float* lu_b_hh = (const float*)d_in[27];
    const float* lu_g_c  = (const float*)d_in[28];
    const float* lu_b_c  = (const float*)d_in[29];

    float* out = (float*)d_out;
    float* l_slab = out;                              // [9, L, 128]
    float* c_slab = out + (size_t)9 * L_SIZE * DIM;   // [9, C, 128]

    // ---- workspace (~232 MB) ----
    char* wp = (char*)d_ws;
    float*  l_state = (float*)wp;  wp += (size_t)L_SIZE * DIM * 4;   // 41.0 MB
    float*  c_state = (float*)wp;  wp += (size_t)C_SIZE * DIM * 4;   // 61.4 MB
    float*  aggr    = (float*)wp;  wp += (size_t)C_SIZE * DIM * 4;   // 61.4 MB
    float*  msg     = (float*)wp;  wp += (size_t)C_SIZE * DIM * 4;   // 61.4 MB
    // CSR structures (built once per call)
    int* c_off     = (int*)wp; wp += (C_SIZE + 1) * 4;
    int* l_off     = (int*)wp; wp += (L_SIZE + 1) * 4;
    int* cnt       = (int*)wp; wp += C_SIZE * 4;      // counts (reused both sides)
    int* cursor    = (int*)wp; wp += C_SIZE * 4;      // fill cursors (reused)
    int* c_srclist = (int*)wp; wp += N_EDGES * 4;     // literal ids, clause-grouped
    int* l_srclist = (int*)wp; wp += N_EDGES * 4;     // clause ids, literal-grouped
    // packed split-bf16 weights
    ushort* l2c_w1Ph = (ushort*)wp; wp += 128 * 128 * 2;
    ushort* l2c_w1Pl = (ushort*)wp; wp += 128 * 128 * 2;
    ushort* l2c_w2Ph = (ushort*)wp; wp += 128 * 128 * 2;
    ushort* l2c_w2Pl = (ushort*)wp; wp += 128 * 128 * 2;
    ushort* c2l_w1Ph = (ushort*)wp; wp += 128 * 128 * 2;
    ushort* c2l_w1Pl = (ushort*)wp; wp += 128 * 128 * 2;
    ushort* c2l_w2Ph = (ushort*)wp; wp += 128 * 128 * 2;
    ushort* c2l_w2Pl = (ushort*)wp; wp += 128 * 128 * 2;
    ushort* cu_wiPh  = (ushort*)wp; wp += 128 * 512 * 2;
    ushort* cu_wiPl  = (ushort*)wp; wp += 128 * 512 * 2;
    ushort* cu_whPh  = (ushort*)wp; wp += 128 * 512 * 2;
    ushort* cu_whPl  = (ushort*)wp; wp += 128 * 512 * 2;
    ushort* lu_wiPh  = (ushort*)wp; wp += 256 * 512 * 2;
    ushort* lu_wiPl  = (ushort*)wp; wp += 256 * 512 * 2;
    ushort* lu_whPh  = (ushort*)wp; wp += 128 * 512 * 2;
    ushort* lu_whPl  = (ushort*)wp; wp += 128 * 512 * 2;

    const int eb = N_EDGES / 256;   // 1875, exact

    // ---- CSR build: clause side (dst = c_edge, src = l_edge) ----
    hipMemsetAsync(cnt, 0, C_SIZE * 4, stream);
    count_kernel<<<eb, 256, 0, stream>>>(c_edge, cnt);
    scan_kernel<<<1, 1024, 0, stream>>>(cnt, c_off, C_SIZE);
    hipMemcpyAsync(cursor, c_off, C_SIZE * 4, hipMemcpyDeviceToDevice, stream);
    fill_kernel<<<eb, 256, 0, stream>>>(l_edge, c_edge, cursor, c_srclist);
    // ---- CSR build: literal side (dst = l_edge, src = c_edge) ----
    hipMemsetAsync(cnt, 0, L_SIZE * 4, stream);
    count_kernel<<<eb, 256, 0, stream>>>(l_edge, cnt);
    scan_kernel<<<1, 1024, 0, stream>>>(cnt, l_off, L_SIZE);
    hipMemcpyAsync(cursor, l_off, L_SIZE * 4, hipMemcpyDeviceToDevice, stream);
    fill_kernel<<<eb, 256, 0, stream>>>(c_edge, l_edge, cursor, l_srclist);

    // pack weights to split-bf16 fragment layout (re-done every call)
    pack_w2<<<64, 256, 0, stream>>>(l2c_w1, l2c_w1Ph, l2c_w1Pl, 128, 128);
    pack_w2<<<64, 256, 0, stream>>>(l2c_w2, l2c_w2Ph, l2c_w2Pl, 128, 128);
    pack_w2<<<64, 256, 0, stream>>>(c2l_w1, c2l_w1Ph, c2l_w1Pl, 128, 128);
    pack_w2<<<64, 256, 0, stream>>>(c2l_w2, c2l_w2Ph, c2l_w2Pl, 128, 128);
    pack_w2<<<256, 256, 0, stream>>>(cu_wi, cu_wiPh, cu_wiPl, 128, 512);
    pack_w2<<<256, 256, 0, stream>>>(cu_wh, cu_whPh, cu_whPl, 128, 512);
    pack_w2<<<512, 256, 0, stream>>>(lu_wi, lu_wiPh, lu_wiPl, 256, 512);
    pack_w2<<<256, 256, 0, stream>>>(lu_wh, lu_whPh, lu_whPl, 128, 512);

    hipMemcpyAsync(l_slab, l_emb0, (size_t)L_SIZE * DIM * sizeof(float),
                   hipMemcpyDeviceToDevice, stream);
    hipMemcpyAsync(c_slab, c_emb0, (size_t)C_SIZE * DIM * sizeof(float),
                   hipMemcpyDeviceToDevice, stream);
    hipMemsetAsync(l_state, 0, (size_t)L_SIZE * DIM * sizeof(float), stream);
    hipMemsetAsync(c_state, 0, (size_t)C_SIZE * DIM * sizeof(float), stream);

    for (int t = 0; t < N_ITER; ++t) {
        const float* le = l_slab + (size_t)t * L_SIZE * DIM;
        const float* ce = c_slab + (size_t)t * C_SIZE * DIM;
        float* le1 = l_slab + (size_t)(t + 1) * L_SIZE * DIM;
        float* ce1 = c_slab + (size_t)(t + 1) * C_SIZE * DIM;

        // ---- literal -> clause ----
        mlp_kernel<<<L_SIZE / 64, 512, 0, stream>>>(le, l2c_w1Ph, l2c_w1Pl, l2c_b1,
                                                    l2c_w2Ph, l2c_w2Pl, l2c_b2, msg);
        aggregate_kernel<<<C_SIZE / 8, 256, 0, stream>>>(msg, c_off, c_srclist,
                                                         aggr, C_SIZE);
        lstm_kernel<4><<<C_SIZE / 32, 512, 0, stream>>>(
            aggr, nullptr, 0, ce, cu_wiPh, cu_wiPl, cu_whPh, cu_whPl,
            cu_g_ih, cu_b_ih, cu_g_hh, cu_b_hh, cu_g_c, cu_b_c,
            c_state, ce1);

        // ---- clause -> literal ----
        mlp_kernel<<<C_SIZE / 64, 512, 0, stream>>>(ce1, c2l_w1Ph, c2l_w1Pl, c2l_b1,
                                                    c2l_w2Ph, c2l_w2Pl, c2l_b2, msg);
        aggregate_kernel<<<L_SIZE / 8, 256, 0, stream>>>(msg, l_off, l_srclist,
                                                         aggr, L_SIZE);
        lstm_kernel<8><<<L_SIZE / 32, 512, 0, stream>>>(
            aggr, le, 1, le, lu_wiPh, lu_wiPl, lu_whPh, lu_whPl,
            lu_g_ih, lu_b_ih, lu_g_hh, lu_b_hh, lu_g_c, lu_b_c,
            l_state, le1);
    }
}